// Round 8
// baseline (140.336 us; speedup 1.0000x reference)
//
#include <hip/hip_runtime.h>
#include <hip/hip_bf16.h>

#define B_ 2
#define T_ 2048
#define C_ 1024
#define NH 16
#define NKV 4
#define HD 64
#define NQKV 1536

typedef __attribute__((ext_vector_type(4))) float f32x4;
typedef __attribute__((ext_vector_type(16))) float f32x16;
typedef __attribute__((ext_vector_type(8))) short bf16x8;

__device__ __forceinline__ unsigned short f2bf(float f) {
  __hip_bfloat16 h = __float2bfloat16(f);
  unsigned short u;
  __builtin_memcpy(&u, &h, 2);
  return u;
}

__device__ __forceinline__ void gload16(const void* g, void* l) {
  __builtin_amdgcn_global_load_lds(
      (const __attribute__((address_space(1))) void*)g,
      (__attribute__((address_space(3))) void*)l, 16, 0, 0);
}

__device__ __forceinline__ unsigned cvtpk(float lo, float hi_) {
  unsigned w;
  asm("v_cvt_pk_bf16_f32 %0, %1, %2" : "=v"(w) : "v"(lo), "v"(hi_));
  return w;
}

__device__ __forceinline__ void swap32(unsigned& x, unsigned& y) {
  asm("v_permlane32_swap_b32 %0, %1" : "+v"(x), "+v"(y));
}

__device__ __forceinline__ bf16x8 mk8(unsigned a, unsigned b, unsigned c, unsigned d) {
  unsigned t[4] = {a, b, c, d};
  bf16x8 r;
  __builtin_memcpy(&r, t, 16);
  return r;
}

// ---------------- fused f32 -> bf16 convert for all 5 tensors (1 launch) ----------------
#define NX4  1048576
#define NW4  262144
#define NK4  65536
#define O1 (NX4)
#define O2 (O1 + NW4)
#define O3 (O2 + NK4)
#define O4 (O3 + NK4)
#define OT (O4 + NW4)

__global__ __launch_bounds__(256) void conv_all(
    const float* __restrict__ x, const float* __restrict__ wq, const float* __restrict__ wk,
    const float* __restrict__ wv, const float* __restrict__ wo,
    unsigned short* __restrict__ xb, unsigned short* __restrict__ wqkvb,
    unsigned short* __restrict__ wob) {
  int i = blockIdx.x * blockDim.x + threadIdx.x;
  const int stride = gridDim.x * blockDim.x;
  for (; i < OT; i += stride) {
    const float* src;
    unsigned short* dst;
    int j;
    if (i < O1)      { src = x;  dst = xb;                    j = i; }
    else if (i < O2) { src = wq; dst = wqkvb;                 j = i - O1; }
    else if (i < O3) { src = wk; dst = wqkvb + 1024 * 1024;   j = i - O2; }
    else if (i < O4) { src = wv; dst = wqkvb + 1280 * 1024;   j = i - O3; }
    else             { src = wo; dst = wob;                   j = i - O4; }
    const float4 v = reinterpret_cast<const float4*>(src)[j];
    ushort4 o;
    o.x = f2bf(v.x); o.y = f2bf(v.y); o.z = f2bf(v.z); o.w = f2bf(v.w);
    reinterpret_cast<ushort4*>(dst)[j] = o;
  }
}

// ---------------- GEMM: C[M,N] = A[M,K] * B[N,K]^T  (bf16 in, f32 out) ----------------
#define BM 128
#define BN 128
#define BK 64

__global__ __launch_bounds__(256) void gemm_bt(const unsigned short* __restrict__ A,
                                               const unsigned short* __restrict__ Bw,
                                               float* __restrict__ C, int M, int N, int K) {
  __shared__ unsigned short Al[BM * BK];
  __shared__ unsigned short Bl[BN * BK];
  const int tid = threadIdx.x;
  const int lane = tid & 63;
  const int wid = tid >> 6;
  const int r = lane & 15, g = lane >> 4;
  const int wm = (wid >> 1) * 64, wn = (wid & 1) * 64;
  const int bm0 = blockIdx.y * BM, bn0 = blockIdx.x * BN;
  const int lrow = lane >> 3;
  const int lcol = ((lane & 7) ^ lrow) * 8;
  const unsigned short* Asrc = A + (size_t)(bm0 + wid * 32 + lrow) * K + lcol;
  const unsigned short* Bsrc = Bw + (size_t)(bn0 + wid * 32 + lrow) * K + lcol;
  const int fsw = (r & 7) << 4;
  const char* Ac = (const char*)Al;
  const char* Bc = (const char*)Bl;
  f32x4 acc[4][4] = {};
  for (int k0 = 0; k0 < K; k0 += BK) {
    __syncthreads();
#pragma unroll
    for (int i = 0; i < 4; ++i) {
      gload16(Asrc + (size_t)(i * 8) * K + k0, Al + (wid * 32 + i * 8) * BK);
      gload16(Bsrc + (size_t)(i * 8) * K + k0, Bl + (wid * 32 + i * 8) * BK);
    }
    __syncthreads();
    bf16x8 af[4][2], bfr[4][2];
#pragma unroll
    for (int mi = 0; mi < 4; ++mi)
#pragma unroll
      for (int s = 0; s < 2; ++s)
        af[mi][s] = *reinterpret_cast<const bf16x8*>(
            Ac + (wm + mi * 16 + r) * 128 + ((s * 64 + g * 16) ^ fsw));
#pragma unroll
    for (int ni = 0; ni < 4; ++ni)
#pragma unroll
      for (int s = 0; s < 2; ++s)
        bfr[ni][s] = *reinterpret_cast<const bf16x8*>(
            Bc + (wn + ni * 16 + r) * 128 + ((s * 64 + g * 16) ^ fsw));
#pragma unroll
    for (int s = 0; s < 2; ++s)
#pragma unroll
      for (int mi = 0; mi < 4; ++mi)
#pragma unroll
        for (int ni = 0; ni < 4; ++ni)
          acc[mi][ni] = __builtin_amdgcn_mfma_f32_16x16x32_bf16(af[mi][s], bfr[ni][s],
                                                                acc[mi][ni], 0, 0, 0);
  }
#pragma unroll
  for (int mi = 0; mi < 4; ++mi)
#pragma unroll
    for (int ni = 0; ni < 4; ++ni) {
      const int row = bm0 + wm + mi * 16 + g * 4;
      const int col = bn0 + wn + ni * 16 + r;
#pragma unroll
      for (int e = 0; e < 4; ++e)
        C[(size_t)(row + e) * N + col] = acc[mi][ni][e];
    }
}

// ---------------- postprocess: rotary + rmsnorm on q,k ; gate+ve on v ----------------
__global__ __launch_bounds__(256) void postproc(
    const float* __restrict__ qkv, const float* __restrict__ x, const float* __restrict__ ve,
    const float* __restrict__ cosb, const float* __restrict__ sinb, const float* __restrict__ Wg,
    unsigned short* __restrict__ Qn, unsigned short* __restrict__ Kn, unsigned short* __restrict__ Vt) {
  const int tok = blockIdx.x;
  const int b = tok / T_, t = tok % T_;
  const int wid = threadIdx.x >> 6, lane = threadIdx.x & 63;
  const float* qrow = qkv + (size_t)tok * NQKV;
  const float c = cosb[t * 32 + (lane & 31)];
  const float s = sinb[t * 32 + (lane & 31)];
  for (int u = wid; u < 24; u += 4) {
    if (u < 20) {
      const int off = (u < 16) ? u * 64 : 1024 + (u - 16) * 64;
      float v0 = qrow[off + lane];
      float p = __shfl_xor(v0, 32);
      float rot = (lane < 32) ? (v0 * c + p * s) : (v0 * c - p * s);
      float sq = rot * rot;
#pragma unroll
      for (int m = 1; m < 64; m <<= 1) sq += __shfl_xor(sq, m);
      float outv = rot * rsqrtf(sq * (1.0f / 64.0f) + 1.1920929e-7f) *
                   ((u < 16) ? 0.21640425613334453f : 1.2f);
      if (u < 16)
        Qn[((size_t)(b * NH + u) * T_ + t) * HD + lane] = f2bf(outv);
      else
        Kn[((size_t)(b * NKV + (u - 16)) * T_ + t) * HD + lane] = f2bf(outv);
    } else {
      const int kv = u - 20;
      float dot = 0.f;
#pragma unroll
      for (int i = 0; i < 12; ++i) dot += x[(size_t)tok * C_ + i] * Wg[kv * 12 + i];
      const float gate = 3.0f / (1.0f + __expf(-dot));
      const float vv = qrow[1280 + kv * 64 + lane] + gate * ve[(size_t)tok * (NKV * HD) + kv * 64 + lane];
      Vt[((size_t)(b * NKV + kv) * HD + lane) * T_ + t] = f2bf(vv);
    }
  }
}

// ---------------- flash attention: 32x32 MFMA, in-register softmax, KV-split-2 --------
// grid (32, NH, B), 256 thr (4 waves). Heavy-first q0, block owns 64 queries.
// wave = (strip, par): strip = wid&1 -> queries [q0+32*strip, +32); par = wid>>1 ->
// computes only key-tiles with index parity == par. All 4 waves cooperatively stage
// K/V (64x64 bf16 each) into double-buffered LDS via global_load_lds w16 (source
// pre-swizzled col ^= (row&7)<<4; rule 21). One barrier/iter; pairs alternate
// compute so their MFMA/softmax chains overlap on the CU.
// S^T = mfma32(A=K, B=Q) (C: col=q=lane&31, row=s=(e&3)+8(e>>2)+4hi); softmax fully
// in-register; P->PV B-frags via 16 cvt_pk_bf16 + 8 permlane32_swap; O^T accumulated.
// End: par=1 dumps (O^T, m, l) into dead K/V LDS; par=0 does flash combine + store.
__global__ __launch_bounds__(256, 5) void attn_fwd(
    const unsigned short* __restrict__ Qn, const unsigned short* __restrict__ Kn,
    const unsigned short* __restrict__ Vt, unsigned short* __restrict__ Y,
    const int* __restrict__ wlp) {
  __shared__ unsigned short Kl[2][64 * 64];   // [s][d] swizzled, 8KB each
  __shared__ unsigned short Vl[2][64 * 64];   // [d][s] swizzled, 8KB each
  const int b = blockIdx.z, h = blockIdx.y;
  const int kvh = h >> 2;
  const int tid = threadIdx.x;
  const int wid = tid >> 6, lane = tid & 63;
  const int l31 = lane & 31, hi = lane >> 5;
  const int strip = wid & 1, par = wid >> 1;
  const int q0 = (gridDim.x - 1 - blockIdx.x) * 64;   // heavy-first
  const int qs = q0 + strip * 32;
  const int q = qs + l31;
  const int wl = *wlp;
  const unsigned short* Kb = Kn + (size_t)(b * NKV + kvh) * T_ * HD;
  const unsigned short* Vb = Vt + (size_t)(b * NKV + kvh) * HD * T_;
  bf16x8 qf[4];
  {
    const unsigned short* Qb = Qn + ((size_t)(b * NH + h) * T_ + q) * HD;
#pragma unroll
    for (int kc = 0; kc < 4; ++kc)
      qf[kc] = *reinterpret_cast<const bf16x8*>(Qb + kc * 16 + hi * 8);
  }
  f32x16 oA = {}, oB = {};
  float mrun = -1e30f, lrun = 0.f;
  int slo = q0 - wl; if (slo < 0) slo = 0;
  slo &= ~63;
  const int nt = (q0 + 63 - slo) / 64 + 1;
  // staging: wave covers 16 rows of K and V per tile (2+2 gload16)
  const int srow8 = lane >> 3;
  const int scol = ((lane & 7) ^ srow8) * 8;   // pre-swizzled source element col

#define STAGE(SB, BUF)                                                                   \
  {                                                                                      \
    _Pragma("unroll")                                                                    \
    for (int u = 0; u < 2; ++u) {                                                        \
      const int br = wid * 16 + u * 8;                                                   \
      gload16(Kb + (size_t)((SB) + br + srow8) * HD + scol, Kl[BUF] + br * 64);          \
      gload16(Vb + (size_t)(br + srow8) * T_ + (SB) + scol, Vl[BUF] + br * 64);          \
    }                                                                                    \
  }

  STAGE(slo, 0);
  __syncthreads();

  const int rA = l31, rB = 32 + l31;
  const int swA = (rA & 7) << 4, swB = (rB & 7) << 4;
  for (int i = 0; i < nt; ++i) {
    const int sb = slo + i * 64;
    if (i + 1 < nt) { STAGE(sb + 64, (i + 1) & 1); }
    if (((i & 1) == par) && sb <= qs + 31 && sb + 63 >= qs - wl) {
      const char* Kc = (const char*)Kl[i & 1];
      const char* Vc = (const char*)Vl[i & 1];
      f32x16 sA = {}, sB = {};
#pragma unroll
      for (int kc = 0; kc < 4; ++kc) {
        const bf16x8 kfA = *reinterpret_cast<const bf16x8*>(Kc + rA * 128 + ((kc * 32 + hi * 16) ^ swA));
        sA = __builtin_amdgcn_mfma_f32_32x32x16_bf16(kfA, qf[kc], sA, 0, 0, 0);
        const bf16x8 kfB = *reinterpret_cast<const bf16x8*>(Kc + rB * 128 + ((kc * 32 + hi * 16) ^ swB));
        sB = __builtin_amdgcn_mfma_f32_32x32x16_bf16(kfB, qf[kc], sB, 0, 0, 0);
      }
      if (sb + 63 > qs || sb < qs + 31 - wl) {   // edge tiles only
#pragma unroll
        for (int e = 0; e < 16; ++e) {
          const int r0 = (e & 3) + 8 * (e >> 2) + 4 * hi;
          const int s0 = sb + r0, s1 = sb + 32 + r0;
          sA[e] = ((unsigned)(q - s0) <= (unsigned)wl) ? sA[e] : -__builtin_inff();
          sB[e] = ((unsigned)(q - s1) <= (unsigned)wl) ? sB[e] : -__builtin_inff();
        }
      }
      float pm = sA[0];
#pragma unroll
      for (int e = 1; e < 16; ++e) pm = fmaxf(pm, sA[e]);
#pragma unroll
      for (int e = 0; e < 16; ++e) pm = fmaxf(pm, sB[e]);
      pm = fmaxf(pm, __shfl_xor(pm, 32));
      if (!__all(pm <= mrun + 8.0f)) {          // defer-max (log2 units)
        const float mnew = fmaxf(mrun, pm);
        const float scl = exp2f(mrun - mnew);
        lrun *= scl;
#pragma unroll
        for (int e = 0; e < 16; ++e) { oA[e] *= scl; oB[e] *= scl; }
        mrun = mnew;
      }
      float ps = 0.f;
      unsigned W0[8], W1[8];
#pragma unroll
      for (int m2 = 0; m2 < 8; ++m2) {
        const float a0 = exp2f(sA[2 * m2] - mrun), a1 = exp2f(sA[2 * m2 + 1] - mrun);
        ps += a0 + a1;
        W0[m2] = cvtpk(a0, a1);
        const float b0 = exp2f(sB[2 * m2] - mrun), b1 = exp2f(sB[2 * m2 + 1] - mrun);
        ps += b0 + b1;
        W1[m2] = cvtpk(b0, b1);
      }
      ps += __shfl_xor(ps, 32);
      lrun += ps;
      bf16x8 pfs[4];
      {
        unsigned x0, x1, y0, y1;
        x0 = W0[0]; y0 = W0[2]; x1 = W0[1]; y1 = W0[3];
        swap32(x0, y0); swap32(x1, y1); pfs[0] = mk8(x0, x1, y0, y1);
        x0 = W0[4]; y0 = W0[6]; x1 = W0[5]; y1 = W0[7];
        swap32(x0, y0); swap32(x1, y1); pfs[1] = mk8(x0, x1, y0, y1);
        x0 = W1[0]; y0 = W1[2]; x1 = W1[1]; y1 = W1[3];
        swap32(x0, y0); swap32(x1, y1); pfs[2] = mk8(x0, x1, y0, y1);
        x0 = W1[4]; y0 = W1[6]; x1 = W1[5]; y1 = W1[7];
        swap32(x0, y0); swap32(x1, y1); pfs[3] = mk8(x0, x1, y0, y1);
      }
#pragma unroll
      for (int ks = 0; ks < 4; ++ks) {
        const bf16x8 vfA = *reinterpret_cast<const bf16x8*>(Vc + rA * 128 + ((ks * 32 + hi * 16) ^ swA));
        oA = __builtin_amdgcn_mfma_f32_32x32x16_bf16(vfA, pfs[ks], oA, 0, 0, 0);
        const bf16x8 vfB = *reinterpret_cast<const bf16x8*>(Vc + rB * 128 + ((ks * 32 + hi * 16) ^ swB));
        oB = __builtin_amdgcn_mfma_f32_32x32x16_bf16(vfB, pfs[ks], oB, 0, 0, 0);
      }
    }
    __syncthreads();
  }
  // ---- combine the two kv-split partials per q-strip (reuse dead K/V LDS) ----
  float* Ox = (float*)Kl;               // [strip][64 d][32 q] f32 = 16KB
  float* ML = (float*)Vl;               // [strip][{m,l}][32 q]
  if (par == 1) {
    float* dst = Ox + strip * 2048;
#pragma unroll
    for (int e = 0; e < 16; ++e) {
      const int d = (e & 3) + 8 * (e >> 2) + 4 * hi;
      dst[d * 32 + l31] = oA[e];
      dst[(d + 32) * 32 + l31] = oB[e];
    }
    if (hi == 0) { ML[strip * 64 + l31] = mrun; ML[strip * 64 + 32 + l31] = lrun; }
  }
  __syncthreads();
  if (par == 0) {
    const float* src = Ox + strip * 2048;
    const float m1 = ML[strip * 64 + l31];
    const float l1 = ML[strip * 64 + 32 + l31];
    const float m = fmaxf(mrun, m1);
    const float a0 = exp2f(mrun - m), a1 = exp2f(m1 - m);
    const float linv = 1.0f / (lrun * a0 + l1 * a1);
    unsigned short* Yp = Y + ((size_t)(b * T_) + q) * (NH * HD) + h * HD + 4 * hi;
#pragma unroll
    for (int E = 0; E < 4; ++E) {
      ushort4 w;
      w.x = f2bf((oA[4 * E + 0] * a0 + src[(8 * E + 4 * hi + 0) * 32 + l31] * a1) * linv);
      w.y = f2bf((oA[4 * E + 1] * a0 + src[(8 * E + 4 * hi + 1) * 32 + l31] * a1) * linv);
      w.z = f2bf((oA[4 * E + 2] * a0 + src[(8 * E + 4 * hi + 2) * 32 + l31] * a1) * linv);
      w.w = f2bf((oA[4 * E + 3] * a0 + src[(8 * E + 4 * hi + 3) * 32 + l31] * a1) * linv);
      *reinterpret_cast<ushort4*>(Yp + E * 8) = w;
      ushort4 v;
      v.x = f2bf((oB[4 * E + 0] * a0 + src[(32 + 8 * E + 4 * hi + 0) * 32 + l31] * a1) * linv);
      v.y = f2bf((oB[4 * E + 1] * a0 + src[(32 + 8 * E + 4 * hi + 1) * 32 + l31] * a1) * linv);
      v.z = f2bf((oB[4 * E + 2] * a0 + src[(32 + 8 * E + 4 * hi + 2) * 32 + l31] * a1) * linv);
      v.w = f2bf((oB[4 * E + 3] * a0 + src[(32 + 8 * E + 4 * hi + 3) * 32 + l31] * a1) * linv);
      *reinterpret_cast<ushort4*>(Yp + 32 + E * 8) = v;
    }
  }
}

extern "C" void kernel_launch(void* const* d_in, const int* in_sizes, int n_in,
                              void* d_out, int out_size, void* d_ws, size_t ws_size,
                              hipStream_t stream) {
  const float* x    = (const float*)d_in[0];
  const float* ve   = (const float*)d_in[1];
  const float* cosb = (const float*)d_in[2];
  const float* sinb = (const float*)d_in[3];
  const float* Wq   = (const float*)d_in[4];
  const float* Wk   = (const float*)d_in[5];
  const float* Wv   = (const float*)d_in[6];
  const float* Wo   = (const float*)d_in[7];
  const float* Wg   = (const float*)d_in[8];
  const int*   wlp  = (const int*)d_in[9];

  char* ws = (char*)d_ws;
  unsigned short* xb    = (unsigned short*)ws; ws += (size_t)4096 * 1024 * 2;
  unsigned short* wqkvb = (unsigned short*)ws; ws += (size_t)1536 * 1024 * 2;
  unsigned short* wob   = (unsigned short*)ws; ws += (size_t)1024 * 1024 * 2;
  float*          qkv   = (float*)ws;          ws += (size_t)4096 * 1536 * 4;
  unsigned short* Qn    = (unsigned short*)ws; ws += (size_t)B_ * NH * T_ * HD * 2;
  unsigned short* Kn    = (unsigned short*)ws; ws += (size_t)B_ * NKV * T_ * HD * 2;
  unsigned short* Vt    = (unsigned short*)ws; ws += (size_t)B_ * NKV * HD * T_ * 2;
  unsigned short* yb    = (unsigned short*)ws; ws += (size_t)4096 * 1024 * 2;

  conv_all<<<dim3(2048), dim3(256), 0, stream>>>(x, Wq, Wk, Wv, Wo, xb, wqkvb, wob);

  gemm_bt<<<dim3(NQKV / BN, 4096 / BM), dim3(256), 0, stream>>>(xb, wqkvb, qkv, 4096, NQKV, 1024);

  postproc<<<dim3(4096), dim3(256), 0, stream>>>(qkv, x, ve, cosb, sinb, Wg, Qn, Kn, Vt);

  attn_fwd<<<dim3(32, NH, B_), dim3(256), 0, stream>>>(Qn, Kn, Vt, yb, wlp);

  gemm_bt<<<dim3(1024 / BN, 4096 / BM), dim3(256), 0, stream>>>(yb, wob, (float*)d_out, 4096, 1024, 1024);
}

// Round 9
// 108.264 us; speedup vs baseline: 1.2962x; 1.2962x over previous
//
#include <hip/hip_runtime.h>
#include <hip/hip_bf16.h>

#define B_ 2
#define T_ 2048
#define C_ 1024
#define NH 16
#define NKV 4
#define HD 64
#define NQKV 1536
#define KVB 64

typedef __attribute__((ext_vector_type(4))) float f32x4;
typedef __attribute__((ext_vector_type(8))) short bf16x8;
typedef __attribute__((ext_vector_type(4))) short bf16x4;

__device__ __forceinline__ unsigned short f2bf(float f) {
  __hip_bfloat16 h = __float2bfloat16(f);
  unsigned short u;
  __builtin_memcpy(&u, &h, 2);
  return u;
}

__device__ __forceinline__ float bf2f(unsigned short u) {
  unsigned v = ((unsigned)u) << 16;
  float f;
  __builtin_memcpy(&f, &v, 4);
  return f;
}

__device__ __forceinline__ void gload16(const void* g, void* l) {
  __builtin_amdgcn_global_load_lds(
      (const __attribute__((address_space(1))) void*)g,
      (__attribute__((address_space(3))) void*)l, 16, 0, 0);
}

// ---------------- fused f32 -> bf16 convert for all 5 tensors (1 launch) ----------------
#define NX4  1048576
#define NW4  262144
#define NK4  65536
#define O1 (NX4)
#define O2 (O1 + NW4)
#define O3 (O2 + NK4)
#define O4 (O3 + NK4)
#define OT (O4 + NW4)

__global__ __launch_bounds__(256) void conv_all(
    const float* __restrict__ x, const float* __restrict__ wq, const float* __restrict__ wk,
    const float* __restrict__ wv, const float* __restrict__ wo,
    unsigned short* __restrict__ xb, unsigned short* __restrict__ wqkvb,
    unsigned short* __restrict__ wob) {
  int i = blockIdx.x * blockDim.x + threadIdx.x;
  const int stride = gridDim.x * blockDim.x;
  for (; i < OT; i += stride) {
    const float* src;
    unsigned short* dst;
    int j;
    if (i < O1)      { src = x;  dst = xb;                    j = i; }
    else if (i < O2) { src = wq; dst = wqkvb;                 j = i - O1; }
    else if (i < O3) { src = wk; dst = wqkvb + 1024 * 1024;   j = i - O2; }
    else if (i < O4) { src = wv; dst = wqkvb + 1280 * 1024;   j = i - O3; }
    else             { src = wo; dst = wob;                   j = i - O4; }
    const float4 v = reinterpret_cast<const float4*>(src)[j];
    ushort4 o;
    o.x = f2bf(v.x); o.y = f2bf(v.y); o.z = f2bf(v.z); o.w = f2bf(v.w);
    reinterpret_cast<ushort4*>(dst)[j] = o;
  }
}

// ---------------- GEMM: C[M,N] = A[M,K] * B[N,K]^T  (bf16 in, f32/bf16 out) ----------------
// m97 structure, BM=128, BN templated (64 -> more blocks/CU for small N). global_load_lds
// w16 staging, source pre-swizzled col^=(row&7)<<4 (rule 21), ds_read applies same XOR.
#define BM 128
#define BK 64

template <int BNT, bool OUTBF>
__global__ __launch_bounds__(256) void gemm_bt(const unsigned short* __restrict__ A,
                                               const unsigned short* __restrict__ Bw,
                                               void* __restrict__ Cv, int M, int N, int K) {
  constexpr int NI = BNT / 32;               // 16-col frags per wave
  __shared__ unsigned short Al[BM * BK];
  __shared__ unsigned short Bl[BNT * BK];
  const int tid = threadIdx.x;
  const int lane = tid & 63;
  const int wid = tid >> 6;
  const int r = lane & 15, g = lane >> 4;
  const int wm = (wid >> 1) * 64, wn = (wid & 1) * (BNT / 2);
  const int bm0 = blockIdx.y * BM, bn0 = blockIdx.x * BNT;
  const int lrow = lane >> 3;
  const int lcol = ((lane & 7) ^ lrow) * 8;  // pre-swizzled source col
  const unsigned short* Asrc = A + (size_t)(bm0 + wid * 32 + lrow) * K + lcol;
  const unsigned short* Bsrc = Bw + (size_t)(bn0 + wid * (BNT / 4) + lrow) * K + lcol;
  const int fsw = (r & 7) << 4;
  const char* Ac = (const char*)Al;
  const char* Bc = (const char*)Bl;
  f32x4 acc[4][NI] = {};
  for (int k0 = 0; k0 < K; k0 += BK) {
    __syncthreads();
#pragma unroll
    for (int i = 0; i < 4; ++i)
      gload16(Asrc + (size_t)(i * 8) * K + k0, Al + (wid * 32 + i * 8) * BK);
#pragma unroll
    for (int i = 0; i < BNT / 32; ++i)
      gload16(Bsrc + (size_t)(i * 8) * K + k0, Bl + (wid * (BNT / 4) + i * 8) * BK);
    __syncthreads();
    bf16x8 af[4][2], bfr[NI][2];
#pragma unroll
    for (int mi = 0; mi < 4; ++mi)
#pragma unroll
      for (int s = 0; s < 2; ++s)
        af[mi][s] = *reinterpret_cast<const bf16x8*>(
            Ac + (wm + mi * 16 + r) * 128 + ((s * 64 + g * 16) ^ fsw));
#pragma unroll
    for (int ni = 0; ni < NI; ++ni)
#pragma unroll
      for (int s = 0; s < 2; ++s)
        bfr[ni][s] = *reinterpret_cast<const bf16x8*>(
            Bc + (wn + ni * 16 + r) * 128 + ((s * 64 + g * 16) ^ fsw));
#pragma unroll
    for (int s = 0; s < 2; ++s)
#pragma unroll
      for (int mi = 0; mi < 4; ++mi)
#pragma unroll
        for (int ni = 0; ni < NI; ++ni)
          acc[mi][ni] = __builtin_amdgcn_mfma_f32_16x16x32_bf16(af[mi][s], bfr[ni][s],
                                                                acc[mi][ni], 0, 0, 0);
  }
#pragma unroll
  for (int mi = 0; mi < 4; ++mi)
#pragma unroll
    for (int ni = 0; ni < NI; ++ni) {
      const int row = bm0 + wm + mi * 16 + g * 4;
      const int col = bn0 + wn + ni * 16 + r;
#pragma unroll
      for (int e = 0; e < 4; ++e) {
        if (OUTBF)
          ((unsigned short*)Cv)[(size_t)(row + e) * N + col] = f2bf(acc[mi][ni][e]);
        else
          ((float*)Cv)[(size_t)(row + e) * N + col] = acc[mi][ni][e];
      }
    }
}

// ---------------- postprocess: rotary + rmsnorm on q,k ; gate+ve on v ----------------
// qkv now bf16. writes Qn [B][NH][T][64] (x QK_SCALE*sm_scale*log2e), Kn [B][NKV][T][64],
// Vt [B][NKV][64][T]
__global__ __launch_bounds__(256) void postproc(
    const unsigned short* __restrict__ qkv, const float* __restrict__ x,
    const float* __restrict__ ve, const float* __restrict__ cosb,
    const float* __restrict__ sinb, const float* __restrict__ Wg,
    unsigned short* __restrict__ Qn, unsigned short* __restrict__ Kn,
    unsigned short* __restrict__ Vt) {
  const int tok = blockIdx.x;
  const int b = tok / T_, t = tok % T_;
  const int wid = threadIdx.x >> 6, lane = threadIdx.x & 63;
  const unsigned short* qrow = qkv + (size_t)tok * NQKV;
  const float c = cosb[t * 32 + (lane & 31)];
  const float s = sinb[t * 32 + (lane & 31)];
  for (int u = wid; u < 24; u += 4) {
    if (u < 20) {
      const int off = (u < 16) ? u * 64 : 1024 + (u - 16) * 64;
      float v0 = bf2f(qrow[off + lane]);
      float p = __shfl_xor(v0, 32);
      float rot = (lane < 32) ? (v0 * c + p * s) : (v0 * c - p * s);
      float sq = rot * rot;
#pragma unroll
      for (int m = 1; m < 64; m <<= 1) sq += __shfl_xor(sq, m);
      float outv = rot * rsqrtf(sq * (1.0f / 64.0f) + 1.1920929e-7f) *
                   ((u < 16) ? 0.21640425613334453f : 1.2f);
      if (u < 16)
        Qn[((size_t)(b * NH + u) * T_ + t) * HD + lane] = f2bf(outv);
      else
        Kn[((size_t)(b * NKV + (u - 16)) * T_ + t) * HD + lane] = f2bf(outv);
    } else {
      const int kv = u - 20;
      float dot = 0.f;
#pragma unroll
      for (int i = 0; i < 12; ++i) dot += x[(size_t)tok * C_ + i] * Wg[kv * 12 + i];
      const float gate = 3.0f / (1.0f + __expf(-dot));
      const float vv = bf2f(qrow[1280 + kv * 64 + lane]) +
                       gate * ve[(size_t)tok * (NKV * HD) + kv * 64 + lane];
      Vt[((size_t)(b * NKV + kv) * HD + lane) * T_ + t] = f2bf(vv);
    }
  }
}

// ---------------- flash attention, sliding window, GQA (R5-proven version) ----------------
// grid (T/64, NH, B), 256 thr. HEAVY-FIRST q0. Block owns 64 queries; wave w owns 16.
// K/V tiles (64x64 bf16) staged cooperatively in double-buffered, XOR-swizzled LDS.
// Async-stage split: next tile's global loads issue before compute; ds_writes after.
// S^T = K*Q^T via mfma(A=K,B=Q); O^T += V^T * P^T; P bounced via swizzled per-wave LDS.
__global__ __launch_bounds__(256, 4) void attn_fwd(
    const unsigned short* __restrict__ Qn, const unsigned short* __restrict__ Kn,
    const unsigned short* __restrict__ Vt, unsigned short* __restrict__ Y,
    const int* __restrict__ wlp) {
  __shared__ unsigned short Kl[2][KVB * 64];
  __shared__ unsigned short Vl[2][64 * KVB];
  __shared__ unsigned short Pl[4][16 * 64];
  const int b = blockIdx.z, h = blockIdx.y;
  const int kvh = h >> 2;
  const int tid = threadIdx.x;
  const int wid = tid >> 6, lane = tid & 63;
  const int q0 = (gridDim.x - 1 - blockIdx.x) * 64;   // heavy-first
  const int qs = q0 + wid * 16;
  const int r = lane & 15, g = lane >> 4;
  const int wl = *wlp;
  const unsigned short* Qb = Qn + ((size_t)(b * NH + h) * T_ + qs) * HD;
  const unsigned short* Kb = Kn + (size_t)(b * NKV + kvh) * T_ * HD;
  const unsigned short* Vb = Vt + (size_t)(b * NKV + kvh) * HD * T_;
  const bf16x8 qf0 = *reinterpret_cast<const bf16x8*>(Qb + r * HD + g * 8);
  const bf16x8 qf1 = *reinterpret_cast<const bf16x8*>(Qb + r * HD + 32 + g * 8);
  float mrun = -1e30f, lrun = 0.f;
  f32x4 o[4] = {};
  int slo = q0 - wl; if (slo < 0) slo = 0;
  slo &= ~63;
  const int send = q0 + 63;
  const int srow = tid >> 3;
  const int scolb = (tid & 7) * 16;
  const int sdst = srow * 128 + (scolb ^ ((srow & 7) << 4));
  const unsigned short* Ksrc0 = Kb + (size_t)srow * HD + (scolb >> 1);
  const unsigned short* Ksrc1 = Kb + (size_t)(srow + 32) * HD + (scolb >> 1);
  const unsigned short* Vsrc0 = Vb + (size_t)srow * T_ + (scolb >> 1);
  const unsigned short* Vsrc1 = Vb + (size_t)(srow + 32) * T_ + (scolb >> 1);
  char* Pwb = (char*)Pl[wid];
  const int swz = (r & 7) << 4;
  const int ksw = swz;
  const int q = qs + r;

  bf16x8 ska, skb, sva, svb;
  ska = *reinterpret_cast<const bf16x8*>(Ksrc0 + (size_t)slo * HD);
  skb = *reinterpret_cast<const bf16x8*>(Ksrc1 + (size_t)slo * HD);
  sva = *reinterpret_cast<const bf16x8*>(Vsrc0 + slo);
  svb = *reinterpret_cast<const bf16x8*>(Vsrc1 + slo);
  {
    char* Kd = (char*)Kl[0]; char* Vd = (char*)Vl[0];
    *reinterpret_cast<bf16x8*>(Kd + sdst) = ska;
    *reinterpret_cast<bf16x8*>(Kd + 32 * 128 + sdst) = skb;
    *reinterpret_cast<bf16x8*>(Vd + sdst) = sva;
    *reinterpret_cast<bf16x8*>(Vd + 32 * 128 + sdst) = svb;
  }
  __syncthreads();

  int cur = 0;
  for (int sb = slo; sb <= send; sb += KVB) {
    const bool has_next = (sb + KVB <= send);
    if (has_next) {
      const int nb = sb + KVB;
      ska = *reinterpret_cast<const bf16x8*>(Ksrc0 + (size_t)nb * HD);
      skb = *reinterpret_cast<const bf16x8*>(Ksrc1 + (size_t)nb * HD);
      sva = *reinterpret_cast<const bf16x8*>(Vsrc0 + nb);
      svb = *reinterpret_cast<const bf16x8*>(Vsrc1 + nb);
    }
    if (sb <= qs + 15) {
      const char* Kc = (const char*)Kl[cur];
      const char* Vc = (const char*)Vl[cur];
      float sv[16];
#pragma unroll
      for (int sub = 0; sub < 4; ++sub) {
        const int rowb = (sub * 16 + r) * 128;
        bf16x8 kf0 = *reinterpret_cast<const bf16x8*>(Kc + rowb + ((g * 16) ^ ksw));
        bf16x8 kf1 = *reinterpret_cast<const bf16x8*>(Kc + rowb + ((64 + g * 16) ^ ksw));
        f32x4 z = {};
        z = __builtin_amdgcn_mfma_f32_16x16x32_bf16(kf0, qf0, z, 0, 0, 0);
        z = __builtin_amdgcn_mfma_f32_16x16x32_bf16(kf1, qf1, z, 0, 0, 0);
#pragma unroll
        for (int e = 0; e < 4; ++e) sv[sub * 4 + e] = z[e];
      }
      if (sb + 63 > qs || sb < qs + 15 - wl) {
#pragma unroll
        for (int i = 0; i < 16; ++i) {
          const int s_ = sb + (i >> 2) * 16 + g * 4 + (i & 3);
          const bool ok = (unsigned)(q - s_) <= (unsigned)wl;
          sv[i] = ok ? sv[i] : -__builtin_inff();
        }
      }
      float pm = sv[0];
#pragma unroll
      for (int i = 1; i < 16; ++i) pm = fmaxf(pm, sv[i]);
      pm = fmaxf(pm, __shfl_xor(pm, 16));
      pm = fmaxf(pm, __shfl_xor(pm, 32));
      if (!__all(pm <= mrun + 8.0f)) {
        const float mnew = fmaxf(mrun, pm);
        const float scl = exp2f(mrun - mnew);
        lrun *= scl;
#pragma unroll
        for (int dt = 0; dt < 4; ++dt)
#pragma unroll
          for (int e = 0; e < 4; ++e) o[dt][e] *= scl;
        mrun = mnew;
      }
      float ps = 0.f;
      unsigned short pb[16];
#pragma unroll
      for (int i = 0; i < 16; ++i) {
        const float p = exp2f(sv[i] - mrun);
        ps += p;
        pb[i] = f2bf(p);
      }
      ps += __shfl_xor(ps, 16);
      ps += __shfl_xor(ps, 32);
      lrun += ps;
#pragma unroll
      for (int sub = 0; sub < 4; ++sub) {
        bf16x4 w;
#pragma unroll
        for (int e = 0; e < 4; ++e) w[e] = (short)pb[sub * 4 + e];
        *reinterpret_cast<bf16x4*>(Pwb + ((r * 128 + sub * 32 + g * 8) ^ swz)) = w;
      }
      asm volatile("s_waitcnt lgkmcnt(0)" ::: "memory");
#pragma unroll
      for (int c = 0; c < 2; ++c) {
        const bf16x8 pf = *reinterpret_cast<const bf16x8*>(Pwb + ((r * 128 + c * 64 + g * 16) ^ swz));
#pragma unroll
        for (int dt = 0; dt < 4; ++dt) {
          const int vrow = (dt * 16 + r) * 128;
          const bf16x8 vf = *reinterpret_cast<const bf16x8*>(Vc + vrow + ((c * 64 + g * 16) ^ ksw));
          o[dt] = __builtin_amdgcn_mfma_f32_16x16x32_bf16(vf, pf, o[dt], 0, 0, 0);
        }
      }
    }
    if (has_next) {
      char* Kd = (char*)Kl[cur ^ 1]; char* Vd = (char*)Vl[cur ^ 1];
      *reinterpret_cast<bf16x8*>(Kd + sdst) = ska;
      *reinterpret_cast<bf16x8*>(Kd + 32 * 128 + sdst) = skb;
      *reinterpret_cast<bf16x8*>(Vd + sdst) = sva;
      *reinterpret_cast<bf16x8*>(Vd + 32 * 128 + sdst) = svb;
    }
    __syncthreads();
    cur ^= 1;
  }
  const float inv = 1.0f / lrun;
  unsigned short* Yb = Y + ((size_t)(b * T_) + qs + r) * (NH * HD) + h * HD;
#pragma unroll
  for (int dt = 0; dt < 4; ++dt)
#pragma unroll
    for (int e = 0; e < 4; ++e)
      Yb[dt * 16 + g * 4 + e] = f2bf(o[dt][e] * inv);
}

extern "C" void kernel_launch(void* const* d_in, const int* in_sizes, int n_in,
                              void* d_out, int out_size, void* d_ws, size_t ws_size,
                              hipStream_t stream) {
  const float* x    = (const float*)d_in[0];
  const float* ve   = (const float*)d_in[1];
  const float* cosb = (const float*)d_in[2];
  const float* sinb = (const float*)d_in[3];
  const float* Wq   = (const float*)d_in[4];
  const float* Wk   = (const float*)d_in[5];
  const float* Wv   = (const float*)d_in[6];
  const float* Wo   = (const float*)d_in[7];
  const float* Wg   = (const float*)d_in[8];
  const int*   wlp  = (const int*)d_in[9];

  char* ws = (char*)d_ws;
  unsigned short* xb    = (unsigned short*)ws; ws += (size_t)4096 * 1024 * 2;
  unsigned short* wqkvb = (unsigned short*)ws; ws += (size_t)1536 * 1024 * 2;
  unsigned short* wob   = (unsigned short*)ws; ws += (size_t)1024 * 1024 * 2;
  unsigned short* qkvb  = (unsigned short*)ws; ws += (size_t)4096 * 1536 * 2;
  unsigned short* Qn    = (unsigned short*)ws; ws += (size_t)B_ * NH * T_ * HD * 2;
  unsigned short* Kn    = (unsigned short*)ws; ws += (size_t)B_ * NKV * T_ * HD * 2;
  unsigned short* Vt    = (unsigned short*)ws; ws += (size_t)B_ * NKV * HD * T_ * 2;
  unsigned short* yb    = (unsigned short*)ws; ws += (size_t)4096 * 1024 * 2;

  conv_all<<<dim3(2048), dim3(256), 0, stream>>>(x, Wq, Wk, Wv, Wo, xb, wqkvb, wob);

  gemm_bt<64, true><<<dim3(NQKV / 64, 4096 / BM), dim3(256), 0, stream>>>(
      xb, wqkvb, (void*)qkvb, 4096, NQKV, 1024);

  postproc<<<dim3(4096), dim3(256), 0, stream>>>(qkvb, x, ve, cosb, sinb, Wg, Qn, Kn, Vt);

  attn_fwd<<<dim3(T_ / 64, NH, B_), dim3(256), 0, stream>>>(Qn, Kn, Vt, yb, wlp);

  gemm_bt<64, false><<<dim3(1024 / 64, 4096 / BM), dim3(256), 0, stream>>>(
      yb, wob, d_out, 4096, 1024, 1024);
}